// Round 1
// baseline (459.489 us; speedup 1.0000x reference)
//
#include <hip/hip_runtime.h>
#include <hip/hip_bf16.h>

typedef __attribute__((ext_vector_type(8))) short bf16x8;
typedef __attribute__((ext_vector_type(8))) unsigned short u16x8;
typedef __attribute__((ext_vector_type(4))) float f32x4;

#define BK 64
#define BM 128
#define BN 128

__device__ __forceinline__ unsigned short f2b(float f) {
    union { float f; unsigned int u; } x; x.f = f;
    unsigned int r = x.u + 0x7fffu + ((x.u >> 16) & 1u);
    return (unsigned short)(r >> 16);
}
__device__ __forceinline__ float b2f(unsigned short b) {
    union { unsigned int u; float f; } x; x.u = ((unsigned int)b) << 16;
    return x.f;
}
__device__ __forceinline__ float sigmoidf_(float v) {
    return 1.0f / (1.0f + __expf(-v));
}
__device__ __forceinline__ float tanhf_(float v) {
    return 1.0f - 2.0f / (__expf(2.0f * v) + 1.0f);
}

__device__ __forceinline__ void gll16(const void* g, void* l) {
    __builtin_amdgcn_global_load_lds(
        (const __attribute__((address_space(1))) void*)g,
        (__attribute__((address_space(3))) void*)l,
        16, 0, 0);
}

#define FENCE() asm volatile("" ::: "memory")
#define BARRIER() do { FENCE(); __builtin_amdgcn_s_barrier(); FENCE(); } while (0)

// ===================== GEMM1: 256x256 tile, 8-wave, 4-phase/K-tile pipeline =====================
// S = Xall(8192x4096) @ Wcat(3072x4096)^T with fused gate epilogues.
// Grid = 512 blocks, 512 threads (8 waves, 2M x 4N), 1 block/CU (128 KiB LDS).
//   f <  256 : r/z gates. bn = f&7 (one bn column per XCD -> 2MB B-panel L2-resident),
//              bm = f>>3, nk = 64.
//   f >= 256 : h gate SPLIT-K (2 slices of 24 k-tiles). Slice s writes shp_s; gemm2 sums
//              shp0+shp1 (+ rh@Uh^T + bh) -> no synchronization needed for split-K.
//   => two perfectly balanced rounds of 256 blocks: makespan 64+24 = 88 K-tile units (ideal).
//
// Per K-tile t, 4 phases. Stage schedule (1 half-tile = 128 rows x 64 cols = 2 gll16/thread):
//   ph0: ds_read A m0-3 (8 b128) + B n0-3 (8 b128); stage A-hi(t+1); MFMA m0-3 x n0-1
//   ph1: stage B-lo(t+2); MFMA m0-3 x n2-3        (B fully LDS-read in ph0 -> B-lo free)
//   ph2: ds_read A m4-7;  stage B-hi(t+2); MFMA m4-7 x n0-1
//   ph3: stage A-lo(t+2); vmcnt(6); MFMA m4-7 x n2-3   (A-lo last read in ph2)
// vmcnt(6) leaves exactly the 3 newest half-tiles (ph1/2/3 of t) in flight and drains
// everything older => K-tile t+1 (A-hi staged ph0(t), rest staged ph1-3(t-1)) is resident.
// Tail (t >= nk-2): stages skipped -> must drain with vmcnt(0).
// LDS XOR swizzle (phys 16B-block p in row r holds global block p ^ (r&7)): conflict-free,
// verified SQ_LDS_BANK_CONFLICT=0 in the 128^2 predecessor; identical per-wave pattern here.
__global__ __launch_bounds__(512, 2) void gemm1(
    const unsigned short* __restrict__ Xall,
    const unsigned short* __restrict__ Wcat,
    const float* __restrict__ hprev,
    const float* __restrict__ br, const float* __restrict__ bz,
    unsigned short* __restrict__ rh,    // bf16 8192x1024
    unsigned short* __restrict__ zs,    // bf16 8192x1024
    unsigned short* __restrict__ shp0,  // bf16 8192x1024 (h preact, K-slice 0)
    unsigned short* __restrict__ shp1)  // bf16 8192x1024 (h preact, K-slice 1)
{
    __shared__ __attribute__((aligned(16))) unsigned short As[2 * 256 * BK];
    __shared__ __attribute__((aligned(16))) unsigned short Bs[2 * 256 * BK];

    const int f = blockIdx.x;
    int bm, bn, tstart, nkt, rfrom, slice = 0;
    if (f < 256) {
        bm = f >> 3; bn = f & 7;              // XCD = f&7 owns bn column
        tstart = 0; nkt = 64; rfrom = 1 << 30;
    } else {
        const int u = f - 256;
        const int x = u & 7;
        bm = u >> 3; bn = 8 + (x >> 1); slice = x & 1;
        tstart = slice * 24; nkt = 24; rfrom = 16;   // k>=16 remaps +1024 (skip dead Uh seg)
    }
    const int m0 = bm * 256;
    const int n0 = bn * 256;

    // staging geometry: thread t covers row (t>>3), phys col-block (t&7);
    // global col-block = phys ^ (row&7). LDS dest = wave-uniform + lane*16 (gll16 req).
    const int st  = threadIdx.x;
    const int sr  = st >> 3;                  // 0..63
    const int scb = st & 7;
    const int ssw = (scb ^ (sr & 7)) * 8;
    const unsigned short* gA = Xall + (size_t)(m0 + sr) * 4096 + ssw;
    const unsigned short* gB = Wcat + (size_t)(n0 + sr) * 4096 + ssw;
    const int lt = sr * BK + scb * 8;

    auto k0f = [&](int tt) -> int {
        const int kp = tstart + tt;
        return kp * 64 + (kp >= rfrom ? 1024 : 0);
    };
    auto stageA = [&](int buf, int half, int k0) {   // 128 rows of A into As[buf]
        const unsigned short* g = gA + (size_t)half * 128 * 4096 + k0;
        unsigned short* l = As + buf * (256 * BK) + half * 128 * BK + lt;
        gll16(g, l);
        gll16(g + (size_t)64 * 4096, l + 64 * BK);
    };
    auto stageB = [&](int buf, int half, int k0) {
        const unsigned short* g = gB + (size_t)half * 128 * 4096 + k0;
        unsigned short* l = Bs + buf * (256 * BK) + half * 128 * BK + lt;
        gll16(g, l);
        gll16(g + (size_t)64 * 4096, l + 64 * BK);
    };

    // prologue: K-tile 0 complete + B(1) + A-lo(1); A-hi(1) staged in ph0(t=0).
    {
        const int k0 = k0f(0);
        stageA(0, 0, k0); stageA(0, 1, k0);
        stageB(0, 0, k0); stageB(0, 1, k0);
        const int k1 = k0f(1);
        stageB(1, 0, k1); stageB(1, 1, k1);
        stageA(1, 0, k1);
        asm volatile("s_waitcnt vmcnt(6)" ::: "memory");  // K-tile 0 resident
        BARRIER();
    }

    const int lane = st & 63;
    const int w = st >> 6;
    const int wm = w >> 2, wn = w & 3;        // 2 x 4 waves; wave tile 128x64
    const int l15 = lane & 15, lhi = lane >> 4, lx = lane & 7;
    const int raBase = (wm * 128 + l15) * BK;
    const int rbBase = (wn * 64 + l15) * BK;
    const int off0 = (lhi ^ lx) * 8;          // kk=0 swizzled block
    const int off1 = ((4 + lhi) ^ lx) * 8;    // kk=1

    f32x4 acc[8][4] = {};
    bf16x8 a[4][2], b[4][2];

    for (int t = 0; t < nkt; ++t) {
        const unsigned short* Ab = As + (t & 1) * (256 * BK);
        const unsigned short* Bb = Bs + (t & 1) * (256 * BK);

        // ---------- phase 0 ----------
        #pragma unroll
        for (int m = 0; m < 4; ++m) {
            a[m][0] = *(const bf16x8*)(Ab + raBase + m * 16 * BK + off0);
            a[m][1] = *(const bf16x8*)(Ab + raBase + m * 16 * BK + off1);
        }
        #pragma unroll
        for (int n = 0; n < 4; ++n) {
            b[n][0] = *(const bf16x8*)(Bb + rbBase + n * 16 * BK + off0);
            b[n][1] = *(const bf16x8*)(Bb + rbBase + n * 16 * BK + off1);
        }
        if (t + 1 < nkt) stageA((t + 1) & 1, 1, k0f(t + 1));   // A-hi(t+1)
        BARRIER();
        asm volatile("s_waitcnt lgkmcnt(0)" ::: "memory");
        __builtin_amdgcn_sched_barrier(0);
        __builtin_amdgcn_s_setprio(1);
        #pragma unroll
        for (int m = 0; m < 4; ++m)
            #pragma unroll
            for (int n = 0; n < 2; ++n) {
                acc[m][n] = __builtin_amdgcn_mfma_f32_16x16x32_bf16(a[m][0], b[n][0], acc[m][n], 0, 0, 0);
                acc[m][n] = __builtin_amdgcn_mfma_f32_16x16x32_bf16(a[m][1], b[n][1], acc[m][n], 0, 0, 0);
            }
        __builtin_amdgcn_s_setprio(0);
        BARRIER();

        // ---------- phase 1 ----------
        if (t + 2 < nkt) stageB(t & 1, 0, k0f(t + 2));         // B-lo(t+2)
        BARRIER();
        __builtin_amdgcn_s_setprio(1);
        #pragma unroll
        for (int m = 0; m < 4; ++m)
            #pragma unroll
            for (int n = 2; n < 4; ++n) {
                acc[m][n] = __builtin_amdgcn_mfma_f32_16x16x32_bf16(a[m][0], b[n][0], acc[m][n], 0, 0, 0);
                acc[m][n] = __builtin_amdgcn_mfma_f32_16x16x32_bf16(a[m][1], b[n][1], acc[m][n], 0, 0, 0);
            }
        __builtin_amdgcn_s_setprio(0);
        BARRIER();

        // ---------- phase 2 ----------
        #pragma unroll
        for (int m = 0; m < 4; ++m) {
            a[m][0] = *(const bf16x8*)(Ab + raBase + (64 + m * 16) * BK + off0);
            a[m][1] = *(const bf16x8*)(Ab + raBase + (64 + m * 16) * BK + off1);
        }
        if (t + 2 < nkt) stageB(t & 1, 1, k0f(t + 2));         // B-hi(t+2)
        BARRIER();
        asm volatile("s_waitcnt lgkmcnt(0)" ::: "memory");
        __builtin_amdgcn_sched_barrier(0);
        __builtin_amdgcn_s_setprio(1);
        #pragma unroll
        for (int m = 0; m < 4; ++m)
            #pragma unroll
            for (int n = 0; n < 2; ++n) {
                acc[4 + m][n] = __builtin_amdgcn_mfma_f32_16x16x32_bf16(a[m][0], b[n][0], acc[4 + m][n], 0, 0, 0);
                acc[4 + m][n] = __builtin_amdgcn_mfma_f32_16x16x32_bf16(a[m][1], b[n][1], acc[4 + m][n], 0, 0, 0);
            }
        __builtin_amdgcn_s_setprio(0);
        BARRIER();

        // ---------- phase 3 ----------
        if (t + 2 < nkt) stageA(t & 1, 0, k0f(t + 2));         // A-lo(t+2)
        if (t >= nkt - 2) asm volatile("s_waitcnt vmcnt(0)" ::: "memory");
        else              asm volatile("s_waitcnt vmcnt(6)" ::: "memory");
        BARRIER();
        __builtin_amdgcn_s_setprio(1);
        #pragma unroll
        for (int m = 0; m < 4; ++m)
            #pragma unroll
            for (int n = 2; n < 4; ++n) {
                acc[4 + m][n] = __builtin_amdgcn_mfma_f32_16x16x32_bf16(a[m][0], b[n][0], acc[4 + m][n], 0, 0, 0);
                acc[4 + m][n] = __builtin_amdgcn_mfma_f32_16x16x32_bf16(a[m][1], b[n][1], acc[4 + m][n], 0, 0, 0);
            }
        __builtin_amdgcn_s_setprio(0);
        BARRIER();
    }

    // ---------- epilogue ----------
    const int rowb = m0 + wm * 128 + lhi * 4;
    if (f < 256) {
        const int gate = bn >> 2;                      // 0=r, 1=z
        const int colb = (n0 - gate * 1024) + wn * 64 + l15;
        if (gate == 0) {
            #pragma unroll
            for (int i = 0; i < 8; ++i)
                #pragma unroll
                for (int r = 0; r < 4; ++r) {
                    const int m = rowb + i * 16 + r;
                    #pragma unroll
                    for (int j = 0; j < 4; ++j) {
                        const int n = colb + j * 16;
                        const size_t idx = (size_t)m * 1024 + n;
                        const float rr = sigmoidf_(acc[i][j][r] + br[n]);
                        rh[idx] = f2b(rr * hprev[idx]);
                    }
                }
        } else {
            #pragma unroll
            for (int i = 0; i < 8; ++i)
                #pragma unroll
                for (int r = 0; r < 4; ++r) {
                    const int m = rowb + i * 16 + r;
                    #pragma unroll
                    for (int j = 0; j < 4; ++j) {
                        const int n = colb + j * 16;
                        const size_t idx = (size_t)m * 1024 + n;
                        zs[idx] = f2b(sigmoidf_(acc[i][j][r] + bz[n]));
                    }
                }
        }
    } else {
        unsigned short* __restrict__ dst = slice ? shp1 : shp0;
        const int colb = (n0 - 2048) + wn * 64 + l15;
        #pragma unroll
        for (int i = 0; i < 8; ++i)
            #pragma unroll
            for (int r = 0; r < 4; ++r) {
                const int m = rowb + i * 16 + r;
                #pragma unroll
                for (int j = 0; j < 4; ++j) {
                    const int n = colb + j * 16;
                    dst[(size_t)m * 1024 + n] = f2b(acc[i][j][r]);
                }
            }
    }
}

// ===================== GEMM2: unchanged 128x128 core =====================
// Core: C[128x128] tile of A(M x lda) * B(N x ldb)^T, both bf16 K-contiguous.
// 4 waves, each 64x64 via 4x4 grid of 16x16x32 MFMAs. XOR-swizzled LDS (conflict-free).
__device__ __forceinline__ void mma_core(
    const unsigned short* __restrict__ A, int lda,
    const unsigned short* __restrict__ B, int ldb,
    int m0, int n0, int nk, int remap_from, int remap_add,
    unsigned short* As, unsigned short* Bs, f32x4 acc[4][4])
{
    const int t = threadIdx.x;
    const int lane = t & 63;
    const int wm = (t >> 7) & 1;
    const int wn = (t >> 6) & 1;
    const int srow = t >> 3;
    const int ldsCol = (t & 7) * 8;
    const int swc = (((t & 7) ^ ((t >> 3) & 7))) * 8;

    for (int kt = 0; kt < nk; ++kt) {
        int k0 = kt * BK + (kt >= remap_from ? remap_add : 0);
        __syncthreads();
        #pragma unroll
        for (int j = 0; j < 4; ++j) {
            int row = j * 32 + srow;
            gll16(A + (size_t)(m0 + row) * lda + k0 + swc, As + row * BK + ldsCol);
            gll16(B + (size_t)(n0 + row) * ldb + k0 + swc, Bs + row * BK + ldsCol);
        }
        __syncthreads();
        #pragma unroll
        for (int kk = 0; kk < 2; ++kk) {
            bf16x8 af[4], bfr[4];
            const int off = (((kk * 4 + (lane >> 4)) ^ (lane & 7))) * 8;
            const int ra = (wm * 64 + (lane & 15)) * BK + off;
            const int rb = (wn * 64 + (lane & 15)) * BK + off;
            #pragma unroll
            for (int i = 0; i < 4; ++i)
                af[i] = *(const bf16x8*)(As + ra + i * 16 * BK);
            #pragma unroll
            for (int j = 0; j < 4; ++j)
                bfr[j] = *(const bf16x8*)(Bs + rb + j * 16 * BK);
            #pragma unroll
            for (int i = 0; i < 4; ++i)
                #pragma unroll
                for (int j = 0; j < 4; ++j)
                    acc[i][j] = __builtin_amdgcn_mfma_f32_16x16x32_bf16(
                        af[i], bfr[j], acc[i][j], 0, 0, 0);
        }
    }
}

// GEMM2: Sh2 = rh(8192x1024) @ Uhb(1024x1024)^T; epilogue: out = z*tanh(Sh2+shp0+shp1+bh)+(1-z)*h.
__global__ __launch_bounds__(256, 4) void gemm2(
    const unsigned short* __restrict__ rh,
    const unsigned short* __restrict__ Uhb,
    const unsigned short* __restrict__ shp0,
    const unsigned short* __restrict__ shp1,
    const float* __restrict__ bh,
    const unsigned short* __restrict__ zs,
    const float* __restrict__ hprev,
    float* __restrict__ out)
{
    __shared__ __attribute__((aligned(16))) unsigned short As[BM * BK];
    __shared__ __attribute__((aligned(16))) unsigned short Bs[BN * BK];
    f32x4 acc[4][4] = {};

    const int flat = blockIdx.y * gridDim.x + blockIdx.x;
    const int xcd = flat & 7;
    const int p = flat >> 3;
    const int bm = xcd * 8 + (p & 7);
    const int bn = p >> 3;
    const int m0 = bm * BM, n0 = bn * BN;

    mma_core(rh, 1024, Uhb, 1024, m0, n0, 16, 1 << 30, 0, As, Bs, acc);

    const int lane = threadIdx.x & 63;
    const int wm = (threadIdx.x >> 7) & 1, wn = (threadIdx.x >> 6) & 1;
    const int rowb = m0 + wm * 64 + (lane >> 4) * 4;
    const int colb = n0 + wn * 64 + (lane & 15);

    #pragma unroll
    for (int i = 0; i < 4; ++i)
        #pragma unroll
        for (int r = 0; r < 4; ++r) {
            int m = rowb + i * 16 + r;
            #pragma unroll
            for (int j = 0; j < 4; ++j) {
                int n = colb + j * 16;
                size_t idx = (size_t)m * 1024 + n;
                float val = acc[i][j][r] + b2f(shp0[idx]) + b2f(shp1[idx]) + bh[n];
                float hp = tanhf_(val);
                float zv = b2f(zs[idx]);
                out[idx] = zv * hp + (1.0f - zv) * hprev[idx];
            }
        }
}

// fp32 -> bf16 strided copy-cast, 12 jobs, flat-indexed (load-balanced).
struct CastJobs {
    const float* src[12];
    unsigned short* dst[12];
    int start[13];
    int cs3[12];
    int stride[12];
};

__global__ __launch_bounds__(256) void cast_all(CastJobs jb, int total) {
    for (int i = blockIdx.x * blockDim.x + threadIdx.x; i < total;
         i += gridDim.x * blockDim.x) {
        int j = 0;
        #pragma unroll
        for (int k = 1; k < 12; ++k) j += (i >= jb.start[k]) ? 1 : 0;
        const int li = i - jb.start[j];
        const float4* src = (const float4*)jb.src[j];
        float4 a = src[2 * li];
        float4 b = src[2 * li + 1];
        const int cs3 = jb.cs3[j];
        int row = li >> cs3;
        int col = (li & ((1 << cs3) - 1)) * 8;
        u16x8 o;
        o[0] = f2b(a.x); o[1] = f2b(a.y); o[2] = f2b(a.z); o[3] = f2b(a.w);
        o[4] = f2b(b.x); o[5] = f2b(b.y); o[6] = f2b(b.z); o[7] = f2b(b.w);
        *(u16x8*)(jb.dst[j] + (size_t)row * jb.stride[j] + col) = o;
    }
}

extern "C" void kernel_launch(void* const* d_in, const int* in_sizes, int n_in,
                              void* d_out, int out_size, void* d_ws, size_t ws_size,
                              hipStream_t stream) {
    const float* x     = (const float*)d_in[0];
    const float* hprev = (const float*)d_in[1];
    const float* c     = (const float*)d_in[2];
    const float* Wh    = (const float*)d_in[3];
    const float* Wz    = (const float*)d_in[4];
    const float* Wr    = (const float*)d_in[5];
    const float* Uh    = (const float*)d_in[6];
    const float* Uz    = (const float*)d_in[7];
    const float* Ur    = (const float*)d_in[8];
    const float* Ch    = (const float*)d_in[9];
    const float* Cz    = (const float*)d_in[10];
    const float* Cr    = (const float*)d_in[11];
    const float* bh    = (const float*)d_in[12];
    const float* bz    = (const float*)d_in[13];
    const float* br    = (const float*)d_in[14];

    char* ws = (char*)d_ws;
    unsigned short* Xall = (unsigned short*)ws; ws += (size_t)8192 * 4096 * 2;
    unsigned short* Wcat = (unsigned short*)ws; ws += (size_t)3072 * 4096 * 2;
    unsigned short* Uhb  = (unsigned short*)ws; ws += (size_t)1024 * 1024 * 2;
    unsigned short* rhb  = (unsigned short*)ws; ws += (size_t)8192 * 1024 * 2;
    unsigned short* shp  = (unsigned short*)ws; ws += (size_t)8192 * 1024 * 2;
    unsigned short* zsb  = (unsigned short*)ws; ws += (size_t)8192 * 1024 * 2;
    unsigned short* shpB = (unsigned short*)ws; ws += (size_t)8192 * 1024 * 2;

    CastJobs jb;
    int acc = 0;
    auto setjob = [&](int j, const float* s, unsigned short* dbase, int col0,
                      int rows, int cols, int stride) {
        jb.src[j] = s; jb.dst[j] = dbase + col0;
        jb.start[j] = acc;
        acc += rows * cols / 8;
        jb.cs3[j] = (cols == 2048) ? 8 : 7;
        jb.stride[j] = stride;
    };
    // Xall = [x | hprev | c]
    setjob(0, x,     Xall, 0,    8192, 1024, 4096);
    setjob(1, hprev, Xall, 1024, 8192, 1024, 4096);
    setjob(2, c,     Xall, 2048, 8192, 2048, 4096);
    // Wcat rows 0..1023 = [Wr|Ur|Cr]
    setjob(3, Wr, Wcat, 0,    1024, 1024, 4096);
    setjob(4, Ur, Wcat, 1024, 1024, 1024, 4096);
    setjob(5, Cr, Wcat, 2048, 1024, 2048, 4096);
    // rows 1024..2047 = [Wz|Uz|Cz]
    setjob(6, Wz, Wcat + 1024 * 4096, 0,    1024, 1024, 4096);
    setjob(7, Uz, Wcat + 1024 * 4096, 1024, 1024, 1024, 4096);
    setjob(8, Cz, Wcat + 1024 * 4096, 2048, 1024, 2048, 4096);
    // rows 2048..3071 = [Wh|unused|Ch] (dead segment never read; h blocks remap k>=16 by +1024)
    setjob(9,  Wh, Wcat + 2048 * 4096, 0,    1024, 1024, 4096);
    setjob(10, Ch, Wcat + 2048 * 4096, 2048, 1024, 2048, 4096);
    // Uh standalone
    setjob(11, Uh, Uhb, 0, 1024, 1024, 1024);
    jb.start[12] = acc;

    hipLaunchKernelGGL(cast_all, dim3(2048), dim3(256), 0, stream, jb, acc);
    hipLaunchKernelGGL(gemm1, dim3(512), dim3(512), 0, stream,
                       Xall, Wcat, hprev, br, bz, rhb, zsb, shp, shpB);
    hipLaunchKernelGGL(gemm2, dim3(8, 64), dim3(256), 0, stream,
                       rhb, Uhb, shp, shpB, bh, zsb, hprev, (float*)d_out);
}